// Round 13
// baseline (4353.624 us; speedup 1.0000x reference)
//
#include <hip/hip_runtime.h>
#include <math.h>

#define D 768

__device__ __forceinline__ void dot4(float& acc, const float4& a, const float4& b) {
  acc += a.x * b.x; acc += a.y * b.y; acc += a.z * b.z; acc += a.w * b.w;
}

// ============================ copy ============================
__global__ __launch_bounds__(256) void copy_f4(const float4* __restrict__ in,
                                               float4* __restrict__ out, int n) {
  int i = blockIdx.x * blockDim.x + threadIdx.x;
  if (i < n) out[i] = in[i];
}

// ============================ row norms ============================
__global__ __launch_bounds__(64) void norms_k(const float* __restrict__ tok,
                                              float* __restrict__ norms, int N) {
  int row = blockIdx.x;
  if (row >= N) return;
  const float* r = tok + (size_t)row * D;
  float s = 0.f;
  for (int k = threadIdx.x; k < D; k += 64) { float v = r[k]; s += v * v; }
#pragma unroll
  for (int off = 32; off > 0; off >>= 1) s += __shfl_down(s, off);
  if (threadIdx.x == 0) norms[row] = sqrtf(s);
}

// ============== cosine-sim v3: 128x128 tile, 8x8/thread, two-phase top-2 ==============
// Decision-equivalence argument (same class as the R5/R6-proven v2):
//  - per-(row,col) dot chain: ascending k, one FMA per k (identical to v1/v2)
//  - top-2 = lexicographic max by (v desc, idx asc); computed by scanning cols
//    ascending in two 64-col phases with register-carried state == one ascending
//    128-col scan; chunks reduced ascending by top2_reduce. Strict > everywhere.
// Ss aliases the As/Bs LDS after the k-loop (barrier-separated). LDS 36.9KB.
__global__ __launch_bounds__(256) void sim_top2_v3(
    const float* __restrict__ tok, const float* __restrict__ norms,
    int nRows, int nCols, int nChunks, float4* __restrict__ part) {
  __shared__ float smem[128 * 72];              // As[128][36] | Bs[128][36]; alias Ss[128][68]
  float* As = smem;
  float* Bs = smem + 128 * 36;
  int tid = threadIdx.x;
  int rowBase = blockIdx.y * 128, colBase = blockIdx.x * 128;
  int tx = tid & 15, ty = tid >> 4;
  float acc[8][8] = {};
  int sr = tid >> 3, sc = (tid & 7) * 4;        // sr 0..31
  for (int kb = 0; kb < D; kb += 32) {
#pragma unroll
    for (int p = 0; p < 4; p++) {
      int r = sr + 32 * p;
      int ga = rowBase + r;
      float4 v = (ga < nRows) ? *(const float4*)&tok[(size_t)ga * D + kb + sc]
                              : make_float4(0.f, 0.f, 0.f, 0.f);
      *(float4*)&As[r * 36 + sc] = v;
      int gb = colBase + r;
      float4 w = (gb < nCols) ? *(const float4*)&tok[(size_t)gb * D + kb + sc]
                              : make_float4(0.f, 0.f, 0.f, 0.f);
      *(float4*)&Bs[r * 36 + sc] = w;
    }
    __syncthreads();
#pragma unroll
    for (int d = 0; d < 32; d += 4) {
      float4 a[8], b[8];
#pragma unroll
      for (int i = 0; i < 8; i++) a[i] = *(float4*)&As[(ty + 16 * i) * 36 + d];
#pragma unroll
      for (int j = 0; j < 8; j++) b[j] = *(float4*)&Bs[(tx + 16 * j) * 36 + d];
#pragma unroll
      for (int i = 0; i < 8; i++)
#pragma unroll
        for (int j = 0; j < 8; j++) dot4(acc[i][j], a[i], b[j]);
    }
    __syncthreads();
  }
  float na[8], nc[8];
#pragma unroll
  for (int i = 0; i < 8; i++) { int r = rowBase + ty + 16 * i; na[i] = (r < nRows) ? norms[r] : 1.f; }
#pragma unroll
  for (int j = 0; j < 8; j++) { int c = colBase + tx + 16 * j; nc[j] = (c < nCols) ? norms[c] : 1.f; }
  float* Ss = smem;                             // [128][68], aliases As/Bs (k-loop done)
  // ---- phase A: cols 0..63 of the tile ----
#pragma unroll
  for (int i = 0; i < 8; i++)
#pragma unroll
    for (int j = 0; j < 4; j++) {
      int c = colBase + tx + 16 * j;
      Ss[(ty + 16 * i) * 68 + tx + 16 * j] =
          (c < nCols) ? acc[i][j] / fmaxf(na[i] * nc[j], 1e-8f) : -INFINITY;
    }
  __syncthreads();
  float v1 = -INFINITY, v2 = -INFINITY;
  int i1 = -1, i2 = -1;
  if (tid < 128) {
    for (int c = 0; c < 64; c++) {
      float v = Ss[tid * 68 + c];
      int id = colBase + c;
      if (v > v1) { v2 = v1; i2 = i1; v1 = v; i1 = id; }
      else if (v > v2) { v2 = v; i2 = id; }
    }
  }
  __syncthreads();
  // ---- phase B: cols 64..127 ----
#pragma unroll
  for (int i = 0; i < 8; i++)
#pragma unroll
    for (int j = 4; j < 8; j++) {
      int c = colBase + tx + 16 * j;
      Ss[(ty + 16 * i) * 68 + tx + 16 * (j - 4)] =
          (c < nCols) ? acc[i][j] / fmaxf(na[i] * nc[j], 1e-8f) : -INFINITY;
    }
  __syncthreads();
  if (tid < 128) {
    int row = rowBase + tid;
    if (row < nRows) {
      for (int c = 0; c < 64; c++) {
        float v = Ss[tid * 68 + c];
        int id = colBase + 64 + c;
        if (v > v1) { v2 = v1; i2 = i1; v1 = v; i1 = id; }
        else if (v > v2) { v2 = v; i2 = id; }
      }
      part[(size_t)row * nChunks + blockIdx.x] =
          make_float4(v1, __int_as_float(i1), v2, __int_as_float(i2));
    }
  }
}

// ============== reduce chunk partials -> final (a,b) pair per row ==============
__global__ __launch_bounds__(256) void top2_reduce(const float4* __restrict__ part,
                                                   int nRows, int nChunks,
                                                   int2* __restrict__ pairs) {
  int row = blockIdx.x * 256 + threadIdx.x;
  if (row >= nRows) return;
  float v1 = -INFINITY, v2 = -INFINITY;
  int i1 = -1, i2 = -1;
  for (int c = 0; c < nChunks; c++) {
    float4 p = part[(size_t)row * nChunks + c];
    float v = p.x; int id = __float_as_int(p.y);
    if (id >= 0) {
      if (v > v1) { v2 = v1; i2 = i1; v1 = v; i1 = id; }
      else if (v > v2) { v2 = v; i2 = id; }
    }
    v = p.z; id = __float_as_int(p.w);
    if (id >= 0) {
      if (v > v1) { v2 = v1; i2 = i1; v1 = v; i1 = id; }
      else if (v > v2) { v2 = v; i2 = id; }
    }
  }
  pairs[row] = make_int2(i1, i2);
}

// ============== merge scan v5 (R10-R12-proven): grouped scan, LDS pairs, L2-sliced ==============
#define MSG 8
__global__ __launch_bounds__(64) void merge_scan5(float* __restrict__ tok,
                                                  const int2* __restrict__ pairs,
                                                  int nm, float wa, float wb) {
  __shared__ int2 sp[4000];
  int t = blockIdx.x * 64 + threadIdx.x;  // column 0..767
  for (int i = threadIdx.x; i < nm; i += 64) sp[i] = pairs[i];
  __syncthreads();
  int s = 0;
  for (; s + MSG <= nm; s += MSG) {
    int aa[MSG], bb[MSG];
    float xx[MSG], yy[MSG], vv[MSG];
#pragma unroll
    for (int c = 0; c < MSG; c++) {
      int2 p = sp[s + c]; aa[c] = p.x; bb[c] = p.y;
    }
#pragma unroll
    for (int c = 0; c < MSG; c++) {
      xx[c] = tok[(size_t)aa[c] * D + t];
      yy[c] = tok[(size_t)bb[c] * D + t];
    }
#pragma unroll
    for (int c = 0; c < MSG; c++) {
      float xv = xx[c], yv = yy[c];
#pragma unroll
      for (int j = 0; j < c; j++) {  // ascending j: latest writer wins
        bool fa = (aa[c] == aa[j]) || (aa[c] == bb[j]);
        bool fb = (bb[c] == aa[j]) || (bb[c] == bb[j]);
        xv = fa ? vv[j] : xv;
        yv = fb ? vv[j] : yv;
      }
      vv[c] = wa * xv + wb * yv;
    }
#pragma unroll
    for (int c = 0; c < MSG; c++) {
      bool la = true, lb = true;
#pragma unroll
      for (int j = c + 1; j < MSG; j++) {
        la = la && (aa[j] != aa[c]) && (bb[j] != aa[c]);
        lb = lb && (aa[j] != bb[c]) && (bb[j] != bb[c]);
      }
      if (la) tok[(size_t)aa[c] * D + t] = vv[c];
      if (lb) tok[(size_t)bb[c] * D + t] = vv[c];
    }
  }
  for (; s < nm; s++) {  // tail (unused for current sizes)
    int2 p = sp[s];
    float x = tok[(size_t)p.x * D + t];
    float y = tok[(size_t)p.y * D + t];
    float v = wa * x + wb * y;
    tok[(size_t)p.x * D + t] = v;
    tok[(size_t)p.y * D + t] = v;
  }
}

// ============== GEMM-NT v2 (R7-R12-proven): C = A @ B^T + bias, opt exact GELU ==============
__global__ __launch_bounds__(256) void gemm_nt_v2(const float* __restrict__ A,
                                                  const float* __restrict__ B,
                                                  const float* __restrict__ bias,
                                                  float* __restrict__ C,
                                                  int M, int N, int K, int act) {
  __shared__ float As[64][36];
  __shared__ float Bs[64][36];
  int tid = threadIdx.x;
  int rowBase = blockIdx.y * 64, colBase = blockIdx.x * 64;
  int tx = tid & 15, ty = tid >> 4;
  float acc[4][4] = {};
  int sr = tid >> 3, sc = (tid & 7) * 4;
  for (int kb = 0; kb < K; kb += 32) {
#pragma unroll
    for (int p = 0; p < 2; p++) {
      int r = sr + 32 * p;
      int ga = rowBase + r;
      float4 v = (ga < M) ? *(const float4*)&A[(size_t)ga * K + kb + sc]
                          : make_float4(0.f, 0.f, 0.f, 0.f);
      *(float4*)&As[r][sc] = v;
      int gb = colBase + r;
      float4 w = (gb < N) ? *(const float4*)&B[(size_t)gb * K + kb + sc]
                          : make_float4(0.f, 0.f, 0.f, 0.f);
      *(float4*)&Bs[r][sc] = w;
    }
    __syncthreads();
#pragma unroll
    for (int d = 0; d < 32; d += 4) {
      float4 a0 = *(float4*)&As[ty][d];
      float4 a1 = *(float4*)&As[ty + 16][d];
      float4 a2 = *(float4*)&As[ty + 32][d];
      float4 a3 = *(float4*)&As[ty + 48][d];
      float4 b0 = *(float4*)&Bs[tx][d];
      float4 b1 = *(float4*)&Bs[tx + 16][d];
      float4 b2 = *(float4*)&Bs[tx + 32][d];
      float4 b3 = *(float4*)&Bs[tx + 48][d];
      dot4(acc[0][0], a0, b0); dot4(acc[0][1], a0, b1); dot4(acc[0][2], a0, b2); dot4(acc[0][3], a0, b3);
      dot4(acc[1][0], a1, b0); dot4(acc[1][1], a1, b1); dot4(acc[1][2], a1, b2); dot4(acc[1][3], a1, b3);
      dot4(acc[2][0], a2, b0); dot4(acc[2][1], a2, b1); dot4(acc[2][2], a2, b2); dot4(acc[2][3], a2, b3);
      dot4(acc[3][0], a3, b0); dot4(acc[3][1], a3, b1); dot4(acc[3][2], a3, b2); dot4(acc[3][3], a3, b3);
    }
    __syncthreads();
  }
#pragma unroll
  for (int i = 0; i < 4; i++)
#pragma unroll
    for (int j = 0; j < 4; j++) {
      int row = rowBase + ty + 16 * i, col = colBase + tx + 16 * j;
      if (row < M && col < N) {
        float v = acc[i][j] + bias[col];
        if (act == 1) v = 0.5f * v * (1.0f + erff(v * 0.70710678118654752f));
        C[(size_t)row * N + col] = v;
      }
    }
}

// ============== fused flash MHA k4 (R12-proven) ==============
#define QT 8
__global__ __launch_bounds__(256) void attn_k4(const float* __restrict__ qkv,
                                               float* __restrict__ attnb, int L) {
  int h = blockIdx.y;
  int q0 = blockIdx.x * QT;
  __shared__ float qs[QT][100];
  __shared__ float ks[64][100];
  __shared__ float vs[64][100];
  __shared__ float ss[QT][68];
  __shared__ float mrow[QT], lrow[QT], corr[QT];
  int tid = threadIdx.x;
  const float scale = 0.10206207261596577f;  // 1/sqrt(96)
  if (tid < QT * 24) {
    int i = tid / 24, c4 = (tid % 24) * 4;
    int qr = q0 + i;
    float4 v = (qr < L) ? *(const float4*)&qkv[(size_t)qr * 2304 + h * 96 + c4]
                        : make_float4(0.f, 0.f, 0.f, 0.f);
    *(float4*)&qs[i][c4] = v;
  }
  if (tid < QT) { mrow[tid] = -INFINITY; lrow[tid] = 0.f; }
  int pi = tid / 24, gpd = tid % 24;
  bool pvact = tid < QT * 24;
  float oa0 = 0.f, oa1 = 0.f, oa2 = 0.f, oa3 = 0.f;
  __syncthreads();
  for (int c0 = 0; c0 < L; c0 += 64) {
    int cn = min(64, L - c0);
    for (int p = tid; p < 64 * 24; p += 256) {
      int r = p / 24, gc = p % 24;
      int pc = 4 * (gc ^ ((r >> 3) & 3));   // swizzled physical col
      bool ok = r < cn;
      float4 kv4 = ok ? *(const float4*)&qkv[(size_t)(c0 + r) * 2304 + 768 + h * 96 + gc * 4]
                      : make_float4(0.f, 0.f, 0.f, 0.f);
      *(float4*)&ks[r][pc] = kv4;
      float4 vv4 = ok ? *(const float4*)&qkv[(size_t)(c0 + r) * 2304 + 1536 + h * 96 + gc * 4]
                      : make_float4(0.f, 0.f, 0.f, 0.f);
      *(float4*)&vs[r][pc] = vv4;
    }
    __syncthreads();
    {
      int qi = tid >> 5;        // 0..7
      int m = tid & 31;         // columns m and m+32
      int swzm = (m >> 3) & 3;  // == ((m+32)>>3)&3
      float a0 = 0.f, a1 = 0.f;
#pragma unroll
      for (int gd = 0; gd < 24; gd++) {   // logical d ascending -> exact chain
        float4 q4 = *(float4*)&qs[qi][4 * gd];
        int pc = 4 * (gd ^ swzm);
        float4 k0 = *(float4*)&ks[m][pc];
        float4 k1 = *(float4*)&ks[m + 32][pc];
        dot4(a0, q4, k0);
        dot4(a1, q4, k1);
      }
      ss[qi][m] = a0 * scale;
      ss[qi][m + 32] = a1 * scale;
    }
    __syncthreads();
    if (tid < QT) {  // softmax: verbatim attn_k2/k3
      int i = tid;
      float m = mrow[i];
      float cm = -INFINITY;
      float sum = 0.f;
      if (cn == 64) {
#pragma unroll
        for (int j = 0; j < 64; j++) cm = fmaxf(cm, ss[i][j]);
        float nm = fmaxf(m, cm);
        float cr = expf(m - nm);
#pragma unroll
        for (int j = 0; j < 64; j++) { float p = expf(ss[i][j] - nm); ss[i][j] = p; sum += p; }
        lrow[i] = lrow[i] * cr + sum;
        mrow[i] = nm;
        corr[i] = cr;
      } else {
        for (int j = 0; j < cn; j++) cm = fmaxf(cm, ss[i][j]);
        float nm = fmaxf(m, cm);
        float cr = expf(m - nm);
        for (int j = 0; j < cn; j++) { float p = expf(ss[i][j] - nm); ss[i][j] = p; sum += p; }
        lrow[i] = lrow[i] * cr + sum;
        mrow[i] = nm;
        corr[i] = cr;
      }
    }
    __syncthreads();
    if (pvact) {
      float cr = corr[pi];
      oa0 *= cr; oa1 *= cr; oa2 *= cr; oa3 *= cr;
      if (cn == 64) {
#pragma unroll
        for (int jg = 0; jg < 16; jg++) {
          int j = 4 * jg;
          float4 s4 = *(float4*)&ss[pi][j];
          int pc = 4 * (gpd ^ ((jg >> 1) & 3));  // (j..j+3 share (j>>3)&3)
          float4 v0 = *(float4*)&vs[j + 0][pc];
          float4 v1 = *(float4*)&vs[j + 1][pc];
          float4 v2 = *(float4*)&vs[j + 2][pc];
          float4 v3 = *(float4*)&vs[j + 3][pc];
          oa0 += s4.x * v0.x; oa1 += s4.x * v0.y; oa2 += s4.x * v0.z; oa3 += s4.x * v0.w;
          oa0 += s4.y * v1.x; oa1 += s4.y * v1.y; oa2 += s4.y * v1.z; oa3 += s4.y * v1.w;
          oa0 += s4.z * v2.x; oa1 += s4.z * v2.y; oa2 += s4.z * v2.z; oa3 += s4.z * v2.w;
          oa0 += s4.w * v3.x; oa1 += s4.w * v3.y; oa2 += s4.w * v3.z; oa3 += s4.w * v3.w;
        }
      } else {
        for (int j = 0; j < cn; j++) {
          float s = ss[pi][j];
          float4 vv = *(float4*)&vs[j][4 * (gpd ^ ((j >> 3) & 3))];
          oa0 += s * vv.x; oa1 += s * vv.y; oa2 += s * vv.z; oa3 += s * vv.w;
        }
      }
    }
    __syncthreads();
  }
  if (pvact) {
    int qr = q0 + pi;
    if (qr < L) {
      float li = lrow[pi];
      float4 o = make_float4(oa0 / li, oa1 / li, oa2 / li, oa3 / li);
      *(float4*)&attnb[(size_t)qr * D + h * 96 + gpd * 4] = o;
    }
  }
}

// ============== residual add + LayerNorm (one row per block) ==============
__global__ __launch_bounds__(256) void res_ln(const float* __restrict__ x,
                                              const float* __restrict__ r,
                                              const float* __restrict__ g,
                                              const float* __restrict__ b,
                                              float* __restrict__ out, int M) {
  int row = blockIdx.x;
  if (row >= M) return;
  __shared__ float buf[D];
  __shared__ float wred[4];
  __shared__ float stats[2];
  int tid = threadIdx.x;
  float s = 0.f;
  for (int k = tid; k < D; k += 256) {
    float v = x[(size_t)row * D + k] + r[(size_t)row * D + k];
    buf[k] = v;
    s += v;
  }
#pragma unroll
  for (int off = 32; off > 0; off >>= 1) s += __shfl_down(s, off);
  if ((tid & 63) == 0) wred[tid >> 6] = s;
  __syncthreads();
  if (tid == 0) stats[0] = (wred[0] + wred[1] + wred[2] + wred[3]) * (1.0f / D);
  __syncthreads();
  float mean = stats[0];
  float s2 = 0.f;
  for (int k = tid; k < D; k += 256) { float d0 = buf[k] - mean; s2 += d0 * d0; }
#pragma unroll
  for (int off = 32; off > 0; off >>= 1) s2 += __shfl_down(s2, off);
  __syncthreads();
  if ((tid & 63) == 0) wred[tid >> 6] = s2;
  __syncthreads();
  if (tid == 0)
    stats[1] = rsqrtf((wred[0] + wred[1] + wred[2] + wred[3]) * (1.0f / D) + 1e-5f);
  __syncthreads();
  float rstd = stats[1];
  for (int k = tid; k < D; k += 256)
    out[(size_t)row * D + k] = (buf[k] - mean) * rstd * g[k] + b[k];
}

// ============================ launcher ============================
extern "C" void kernel_launch(void* const* d_in, const int* in_sizes, int n_in,
                              void* d_out, int out_size, void* d_ws, size_t ws_size,
                              hipStream_t stream) {
  (void)in_sizes; (void)n_in; (void)out_size; (void)ws_size;
  const float* vf   = (const float*)d_in[0];
  const float* Wqkv = (const float*)d_in[1];
  const float* bqkv = (const float*)d_in[2];
  const float* Wo   = (const float*)d_in[3];
  const float* bo   = (const float*)d_in[4];
  const float* ln1g = (const float*)d_in[5];
  const float* ln1b = (const float*)d_in[6];
  const float* W1   = (const float*)d_in[7];
  const float* b1   = (const float*)d_in[8];
  const float* W2   = (const float*)d_in[9];
  const float* b2   = (const float*)d_in[10];
  const float* ln2g = (const float*)d_in[11];
  const float* ln2b = (const float*)d_in[12];

  float* ws = (float*)d_ws;
  float*  tok   = ws;                                // 8000*768
  float*  norms = ws + 6144000;                      // 8000
  float4* part  = (float4*)(ws + 6152000);           // up to 4000*125 float4
  int2*   pairs = (int2*)(ws + 8152000);             // up to 4000 int2
  float*  qkv   = ws + 8160000;                      // 2000*2304
  float*  attnb = ws + 12768000;                     // 2000*768
  float*  projb = ws + 8160000;                      // reuse (qkv dead)
  float*  hid   = ws + 8160000;                      // reuse 1500*3072
  float*  ffnb  = ws + 12768000;                     // reuse (attnb dead)
  float*  outp  = (float*)d_out;

  copy_f4<<<6000, 256, 0, stream>>>((const float4*)vf, (float4*)tok, 1536000);

  // ---- merge 1: 8000 -> 4000, wa=wb=0.5 ----
  norms_k<<<8000, 64, 0, stream>>>(tok, norms, 8000);
  sim_top2_v3<<<dim3(63, 32), 256, 0, stream>>>(tok, norms, 4000, 8000, 63, part);
  top2_reduce<<<(4000 + 255) / 256, 256, 0, stream>>>(part, 4000, 63, pairs);
  merge_scan5<<<12, 64, 0, stream>>>(tok, pairs, 4000, 0.5f, 0.5f);

  // ---- merge 2: 4000 -> 2000, wa=wb=0.5 ----
  norms_k<<<4000, 64, 0, stream>>>(tok, norms, 4000);
  sim_top2_v3<<<dim3(32, 16), 256, 0, stream>>>(tok, norms, 2000, 4000, 32, part);
  top2_reduce<<<(2000 + 255) / 256, 256, 0, stream>>>(part, 2000, 32, pairs);
  merge_scan5<<<12, 64, 0, stream>>>(tok, pairs, 2000, 0.5f, 0.5f);

  // ---- MHA over 2000 tokens ----
  gemm_nt_v2<<<dim3(36, 32), 256, 0, stream>>>(tok, Wqkv, bqkv, qkv, 2000, 2304, 768, 0);
  attn_k4<<<dim3(2000 / QT, 8), 256, 0, stream>>>(qkv, attnb, 2000);
  gemm_nt_v2<<<dim3(12, 32), 256, 0, stream>>>(attnb, Wo, bo, projb, 2000, 768, 768, 0);
  res_ln<<<2000, 256, 0, stream>>>(tok, projb, ln1g, ln1b, tok, 2000);

  // ---- merge 3: 2000 -> 1500, wa=0.6, wb=0.4 ----
  norms_k<<<2000, 64, 0, stream>>>(tok, norms, 2000);
  sim_top2_v3<<<dim3(16, 4), 256, 0, stream>>>(tok, norms, 500, 2000, 16, part);
  top2_reduce<<<(500 + 255) / 256, 256, 0, stream>>>(part, 500, 16, pairs);
  merge_scan5<<<12, 64, 0, stream>>>(tok, pairs, 500, 0.6f, 0.4f);

  // ---- FFN + final LN -> d_out ----
  gemm_nt_v2<<<dim3(48, 24), 256, 0, stream>>>(tok, W1, b1, hid, 1500, 3072, 768, 1);
  gemm_nt_v2<<<dim3(12, 24), 256, 0, stream>>>(hid, W2, b2, ffnb, 1500, 768, 3072, 0);
  res_ln<<<1500, 256, 0, stream>>>(tok, ffnb, ln2g, ln2b, outp, 1500);
}

// Round 14
// 4212.651 us; speedup vs baseline: 1.0335x; 1.0335x over previous
//
#include <hip/hip_runtime.h>
#include <math.h>

#define D 768

__device__ __forceinline__ void dot4(float& acc, const float4& a, const float4& b) {
  acc += a.x * b.x; acc += a.y * b.y; acc += a.z * b.z; acc += a.w * b.w;
}

// ============================ copy ============================
__global__ __launch_bounds__(256) void copy_f4(const float4* __restrict__ in,
                                               float4* __restrict__ out, int n) {
  int i = blockIdx.x * blockDim.x + threadIdx.x;
  if (i < n) out[i] = in[i];
}

// ============================ row norms ============================
__global__ __launch_bounds__(64) void norms_k(const float* __restrict__ tok,
                                              float* __restrict__ norms, int N) {
  int row = blockIdx.x;
  if (row >= N) return;
  const float* r = tok + (size_t)row * D;
  float s = 0.f;
  for (int k = threadIdx.x; k < D; k += 64) { float v = r[k]; s += v * v; }
#pragma unroll
  for (int off = 32; off > 0; off >>= 1) s += __shfl_down(s, off);
  if (threadIdx.x == 0) norms[row] = sqrtf(s);
}

// ============== cosine-sim 64x64 tile + per-row top-2 partial (R8-R12-proven; v3 reverted) ==============
__global__ __launch_bounds__(256) void sim_top2_v2(
    const float* __restrict__ tok, const float* __restrict__ norms,
    int nRows, int nCols, int nChunks, float4* __restrict__ part) {
  __shared__ float As[64][36];
  __shared__ float Bs[64][36];
  __shared__ float Ss[64][68];
  int tid = threadIdx.x;
  int rowBase = blockIdx.y * 64, colBase = blockIdx.x * 64;
  int tx = tid & 15, ty = tid >> 4;
  float acc[4][4] = {};
  int sr = tid >> 3, sc = (tid & 7) * 4;
  for (int kb = 0; kb < D; kb += 32) {
#pragma unroll
    for (int p = 0; p < 2; p++) {
      int r = sr + 32 * p;
      int ga = rowBase + r;
      float4 v = (ga < nRows) ? *(const float4*)&tok[(size_t)ga * D + kb + sc]
                              : make_float4(0.f, 0.f, 0.f, 0.f);
      *(float4*)&As[r][sc] = v;
      int gb = colBase + r;
      float4 w = (gb < nCols) ? *(const float4*)&tok[(size_t)gb * D + kb + sc]
                              : make_float4(0.f, 0.f, 0.f, 0.f);
      *(float4*)&Bs[r][sc] = w;
    }
    __syncthreads();
#pragma unroll
    for (int d = 0; d < 32; d += 4) {
      float4 a0 = *(float4*)&As[ty][d];
      float4 a1 = *(float4*)&As[ty + 16][d];
      float4 a2 = *(float4*)&As[ty + 32][d];
      float4 a3 = *(float4*)&As[ty + 48][d];
      float4 b0 = *(float4*)&Bs[tx][d];
      float4 b1 = *(float4*)&Bs[tx + 16][d];
      float4 b2 = *(float4*)&Bs[tx + 32][d];
      float4 b3 = *(float4*)&Bs[tx + 48][d];
      dot4(acc[0][0], a0, b0); dot4(acc[0][1], a0, b1); dot4(acc[0][2], a0, b2); dot4(acc[0][3], a0, b3);
      dot4(acc[1][0], a1, b0); dot4(acc[1][1], a1, b1); dot4(acc[1][2], a1, b2); dot4(acc[1][3], a1, b3);
      dot4(acc[2][0], a2, b0); dot4(acc[2][1], a2, b1); dot4(acc[2][2], a2, b2); dot4(acc[2][3], a2, b3);
      dot4(acc[3][0], a3, b0); dot4(acc[3][1], a3, b1); dot4(acc[3][2], a3, b2); dot4(acc[3][3], a3, b3);
    }
    __syncthreads();
  }
  float na[4], nc[4];
#pragma unroll
  for (int i = 0; i < 4; i++) { int r = rowBase + ty + 16 * i; na[i] = (r < nRows) ? norms[r] : 1.f; }
#pragma unroll
  for (int j = 0; j < 4; j++) { int c = colBase + tx + 16 * j; nc[j] = (c < nCols) ? norms[c] : 1.f; }
#pragma unroll
  for (int i = 0; i < 4; i++)
#pragma unroll
    for (int j = 0; j < 4; j++) {
      int c = colBase + tx + 16 * j;
      Ss[ty + 16 * i][tx + 16 * j] =
          (c < nCols) ? acc[i][j] / fmaxf(na[i] * nc[j], 1e-8f) : -INFINITY;
    }
  __syncthreads();
  if (tid < 64) {
    int row = rowBase + tid;
    if (row < nRows) {
      float v1 = -INFINITY, v2 = -INFINITY;
      int i1 = -1, i2 = -1;
      for (int c = 0; c < 64; c++) {
        float v = Ss[tid][c];
        int id = colBase + c;
        if (v > v1) { v2 = v1; i2 = i1; v1 = v; i1 = id; }
        else if (v > v2) { v2 = v; i2 = id; }
      }
      part[(size_t)row * nChunks + blockIdx.x] =
          make_float4(v1, __int_as_float(i1), v2, __int_as_float(i2));
    }
  }
}

// ============== reduce chunk partials -> final (a,b) pair per row ==============
__global__ __launch_bounds__(256) void top2_reduce(const float4* __restrict__ part,
                                                   int nRows, int nChunks,
                                                   int2* __restrict__ pairs) {
  int row = blockIdx.x * 256 + threadIdx.x;
  if (row >= nRows) return;
  float v1 = -INFINITY, v2 = -INFINITY;
  int i1 = -1, i2 = -1;
  for (int c = 0; c < nChunks; c++) {
    float4 p = part[(size_t)row * nChunks + c];
    float v = p.x; int id = __float_as_int(p.y);
    if (id >= 0) {
      if (v > v1) { v2 = v1; i2 = i1; v1 = v; i1 = id; }
      else if (v > v2) { v2 = v; i2 = id; }
    }
    v = p.z; id = __float_as_int(p.w);
    if (id >= 0) {
      if (v > v1) { v2 = v1; i2 = i1; v1 = v; i1 = id; }
      else if (v > v2) { v2 = v; i2 = id; }
    }
  }
  pairs[row] = make_int2(i1, i2);
}

// ============== merge scan v5 (R10-R13-proven): grouped scan, LDS pairs, L2-sliced ==============
#define MSG 8
__global__ __launch_bounds__(64) void merge_scan5(float* __restrict__ tok,
                                                  const int2* __restrict__ pairs,
                                                  int nm, float wa, float wb) {
  __shared__ int2 sp[4000];
  int t = blockIdx.x * 64 + threadIdx.x;  // column 0..767
  for (int i = threadIdx.x; i < nm; i += 64) sp[i] = pairs[i];
  __syncthreads();
  int s = 0;
  for (; s + MSG <= nm; s += MSG) {
    int aa[MSG], bb[MSG];
    float xx[MSG], yy[MSG], vv[MSG];
#pragma unroll
    for (int c = 0; c < MSG; c++) {
      int2 p = sp[s + c]; aa[c] = p.x; bb[c] = p.y;
    }
#pragma unroll
    for (int c = 0; c < MSG; c++) {
      xx[c] = tok[(size_t)aa[c] * D + t];
      yy[c] = tok[(size_t)bb[c] * D + t];
    }
#pragma unroll
    for (int c = 0; c < MSG; c++) {
      float xv = xx[c], yv = yy[c];
#pragma unroll
      for (int j = 0; j < c; j++) {  // ascending j: latest writer wins
        bool fa = (aa[c] == aa[j]) || (aa[c] == bb[j]);
        bool fb = (bb[c] == aa[j]) || (bb[c] == bb[j]);
        xv = fa ? vv[j] : xv;
        yv = fb ? vv[j] : yv;
      }
      vv[c] = wa * xv + wb * yv;
    }
#pragma unroll
    for (int c = 0; c < MSG; c++) {
      bool la = true, lb = true;
#pragma unroll
      for (int j = c + 1; j < MSG; j++) {
        la = la && (aa[j] != aa[c]) && (bb[j] != aa[c]);
        lb = lb && (aa[j] != bb[c]) && (bb[j] != bb[c]);
      }
      if (la) tok[(size_t)aa[c] * D + t] = vv[c];
      if (lb) tok[(size_t)bb[c] * D + t] = vv[c];
    }
  }
  for (; s < nm; s++) {  // tail (unused for current sizes)
    int2 p = sp[s];
    float x = tok[(size_t)p.x * D + t];
    float y = tok[(size_t)p.y * D + t];
    float v = wa * x + wb * y;
    tok[(size_t)p.x * D + t] = v;
    tok[(size_t)p.y * D + t] = v;
  }
}

// ============== GEMM-NT v2 (R7-R13-proven): C = A @ B^T + bias, opt exact GELU ==============
__global__ __launch_bounds__(256) void gemm_nt_v2(const float* __restrict__ A,
                                                  const float* __restrict__ B,
                                                  const float* __restrict__ bias,
                                                  float* __restrict__ C,
                                                  int M, int N, int K, int act) {
  __shared__ float As[64][36];
  __shared__ float Bs[64][36];
  int tid = threadIdx.x;
  int rowBase = blockIdx.y * 64, colBase = blockIdx.x * 64;
  int tx = tid & 15, ty = tid >> 4;
  float acc[4][4] = {};
  int sr = tid >> 3, sc = (tid & 7) * 4;
  for (int kb = 0; kb < K; kb += 32) {
#pragma unroll
    for (int p = 0; p < 2; p++) {
      int r = sr + 32 * p;
      int ga = rowBase + r;
      float4 v = (ga < M) ? *(const float4*)&A[(size_t)ga * K + kb + sc]
                          : make_float4(0.f, 0.f, 0.f, 0.f);
      *(float4*)&As[r][sc] = v;
      int gb = colBase + r;
      float4 w = (gb < N) ? *(const float4*)&B[(size_t)gb * K + kb + sc]
                          : make_float4(0.f, 0.f, 0.f, 0.f);
      *(float4*)&Bs[r][sc] = w;
    }
    __syncthreads();
#pragma unroll
    for (int d = 0; d < 32; d += 4) {
      float4 a0 = *(float4*)&As[ty][d];
      float4 a1 = *(float4*)&As[ty + 16][d];
      float4 a2 = *(float4*)&As[ty + 32][d];
      float4 a3 = *(float4*)&As[ty + 48][d];
      float4 b0 = *(float4*)&Bs[tx][d];
      float4 b1 = *(float4*)&Bs[tx + 16][d];
      float4 b2 = *(float4*)&Bs[tx + 32][d];
      float4 b3 = *(float4*)&Bs[tx + 48][d];
      dot4(acc[0][0], a0, b0); dot4(acc[0][1], a0, b1); dot4(acc[0][2], a0, b2); dot4(acc[0][3], a0, b3);
      dot4(acc[1][0], a1, b0); dot4(acc[1][1], a1, b1); dot4(acc[1][2], a1, b2); dot4(acc[1][3], a1, b3);
      dot4(acc[2][0], a2, b0); dot4(acc[2][1], a2, b1); dot4(acc[2][2], a2, b2); dot4(acc[2][3], a2, b3);
      dot4(acc[3][0], a3, b0); dot4(acc[3][1], a3, b1); dot4(acc[3][2], a3, b2); dot4(acc[3][3], a3, b3);
    }
    __syncthreads();
  }
#pragma unroll
  for (int i = 0; i < 4; i++)
#pragma unroll
    for (int j = 0; j < 4; j++) {
      int row = rowBase + ty + 16 * i, col = colBase + tx + 16 * j;
      if (row < M && col < N) {
        float v = acc[i][j] + bias[col];
        if (act == 1) v = 0.5f * v * (1.0f + erff(v * 0.70710678118654752f));
        C[(size_t)row * N + col] = v;
      }
    }
}

// ============== fused flash MHA k5: attn_k4 with QT 8->16, 512 threads ==============
// Pure parameter scaling of R12/R13-proven attn_k4 — per-thread QK/PV/softmax
// code and chains identical; only the q-tile size, block size, and staging
// strides change. LDS 62.1KB -> 2 blocks x 512 thr/CU = 16 waves/CU (2x occ).
#define QT5 16
__global__ __launch_bounds__(512) void attn_k5(const float* __restrict__ qkv,
                                               float* __restrict__ attnb, int L) {
  int h = blockIdx.y;
  int q0 = blockIdx.x * QT5;
  __shared__ float qs[QT5][100];
  __shared__ float ks[64][100];
  __shared__ float vs[64][100];
  __shared__ float ss[QT5][68];
  __shared__ float mrow[QT5], lrow[QT5], corr[QT5];
  int tid = threadIdx.x;
  const float scale = 0.10206207261596577f;  // 1/sqrt(96)
  if (tid < QT5 * 24) {
    int i = tid / 24, c4 = (tid % 24) * 4;
    int qr = q0 + i;
    float4 v = (qr < L) ? *(const float4*)&qkv[(size_t)qr * 2304 + h * 96 + c4]
                        : make_float4(0.f, 0.f, 0.f, 0.f);
    *(float4*)&qs[i][c4] = v;
  }
  if (tid < QT5) { mrow[tid] = -INFINITY; lrow[tid] = 0.f; }
  int pi = tid / 24, gpd = tid % 24;
  bool pvact = tid < QT5 * 24;
  float oa0 = 0.f, oa1 = 0.f, oa2 = 0.f, oa3 = 0.f;
  __syncthreads();
  for (int c0 = 0; c0 < L; c0 += 64) {
    int cn = min(64, L - c0);
    for (int p = tid; p < 64 * 24; p += 512) {
      int r = p / 24, gc = p % 24;
      int pc = 4 * (gc ^ ((r >> 3) & 3));   // swizzled physical col
      bool ok = r < cn;
      float4 kv4 = ok ? *(const float4*)&qkv[(size_t)(c0 + r) * 2304 + 768 + h * 96 + gc * 4]
                      : make_float4(0.f, 0.f, 0.f, 0.f);
      *(float4*)&ks[r][pc] = kv4;
      float4 vv4 = ok ? *(const float4*)&qkv[(size_t)(c0 + r) * 2304 + 1536 + h * 96 + gc * 4]
                      : make_float4(0.f, 0.f, 0.f, 0.f);
      *(float4*)&vs[r][pc] = vv4;
    }
    __syncthreads();
    {
      int qi = tid >> 5;        // 0..15
      int m = tid & 31;         // columns m and m+32
      int swzm = (m >> 3) & 3;  // == ((m+32)>>3)&3
      float a0 = 0.f, a1 = 0.f;
#pragma unroll
      for (int gd = 0; gd < 24; gd++) {   // logical d ascending -> exact chain
        float4 q4 = *(float4*)&qs[qi][4 * gd];
        int pc = 4 * (gd ^ swzm);
        float4 k0 = *(float4*)&ks[m][pc];
        float4 k1 = *(float4*)&ks[m + 32][pc];
        dot4(a0, q4, k0);
        dot4(a1, q4, k1);
      }
      ss[qi][m] = a0 * scale;
      ss[qi][m + 32] = a1 * scale;
    }
    __syncthreads();
    if (tid < QT5) {  // softmax: verbatim attn_k2/k3/k4
      int i = tid;
      float m = mrow[i];
      float cm = -INFINITY;
      float sum = 0.f;
      if (cn == 64) {
#pragma unroll
        for (int j = 0; j < 64; j++) cm = fmaxf(cm, ss[i][j]);
        float nm = fmaxf(m, cm);
        float cr = expf(m - nm);
#pragma unroll
        for (int j = 0; j < 64; j++) { float p = expf(ss[i][j] - nm); ss[i][j] = p; sum += p; }
        lrow[i] = lrow[i] * cr + sum;
        mrow[i] = nm;
        corr[i] = cr;
      } else {
        for (int j = 0; j < cn; j++) cm = fmaxf(cm, ss[i][j]);
        float nm = fmaxf(m, cm);
        float cr = expf(m - nm);
        for (int j = 0; j < cn; j++) { float p = expf(ss[i][j] - nm); ss[i][j] = p; sum += p; }
        lrow[i] = lrow[i] * cr + sum;
        mrow[i] = nm;
        corr[i] = cr;
      }
    }
    __syncthreads();
    if (pvact) {
      float cr = corr[pi];
      oa0 *= cr; oa1 *= cr; oa2 *= cr; oa3 *= cr;
      if (cn == 64) {
#pragma unroll
        for (int jg = 0; jg < 16; jg++) {
          int j = 4 * jg;
          float4 s4 = *(float4*)&ss[pi][j];
          int pc = 4 * (gpd ^ ((jg >> 1) & 3));  // (j..j+3 share (j>>3)&3)
          float4 v0 = *(float4*)&vs[j + 0][pc];
          float4 v1 = *(float4*)&vs[j + 1][pc];
          float4 v2 = *(float4*)&vs[j + 2][pc];
          float4 v3 = *(float4*)&vs[j + 3][pc];
          oa0 += s4.x * v0.x; oa1 += s4.x * v0.y; oa2 += s4.x * v0.z; oa3 += s4.x * v0.w;
          oa0 += s4.y * v1.x; oa1 += s4.y * v1.y; oa2 += s4.y * v1.z; oa3 += s4.y * v1.w;
          oa0 += s4.z * v2.x; oa1 += s4.z * v2.y; oa2 += s4.z * v2.z; oa3 += s4.z * v2.w;
          oa0 += s4.w * v3.x; oa1 += s4.w * v3.y; oa2 += s4.w * v3.z; oa3 += s4.w * v3.w;
        }
      } else {
        for (int j = 0; j < cn; j++) {
          float s = ss[pi][j];
          float4 vv = *(float4*)&vs[j][4 * (gpd ^ ((j >> 3) & 3))];
          oa0 += s * vv.x; oa1 += s * vv.y; oa2 += s * vv.z; oa3 += s * vv.w;
        }
      }
    }
    __syncthreads();
  }
  if (pvact) {
    int qr = q0 + pi;
    if (qr < L) {
      float li = lrow[pi];
      float4 o = make_float4(oa0 / li, oa1 / li, oa2 / li, oa3 / li);
      *(float4*)&attnb[(size_t)qr * D + h * 96 + gpd * 4] = o;
    }
  }
}

// ============== residual add + LayerNorm (one row per block) ==============
__global__ __launch_bounds__(256) void res_ln(const float* __restrict__ x,
                                              const float* __restrict__ r,
                                              const float* __restrict__ g,
                                              const float* __restrict__ b,
                                              float* __restrict__ out, int M) {
  int row = blockIdx.x;
  if (row >= M) return;
  __shared__ float buf[D];
  __shared__ float wred[4];
  __shared__ float stats[2];
  int tid = threadIdx.x;
  float s = 0.f;
  for (int k = tid; k < D; k += 256) {
    float v = x[(size_t)row * D + k] + r[(size_t)row * D + k];
    buf[k] = v;
    s += v;
  }
#pragma unroll
  for (int off = 32; off > 0; off >>= 1) s += __shfl_down(s, off);
  if ((tid & 63) == 0) wred[tid >> 6] = s;
  __syncthreads();
  if (tid == 0) stats[0] = (wred[0] + wred[1] + wred[2] + wred[3]) * (1.0f / D);
  __syncthreads();
  float mean = stats[0];
  float s2 = 0.f;
  for (int k = tid; k < D; k += 256) { float d0 = buf[k] - mean; s2 += d0 * d0; }
#pragma unroll
  for (int off = 32; off > 0; off >>= 1) s2 += __shfl_down(s2, off);
  __syncthreads();
  if ((tid & 63) == 0) wred[tid >> 6] = s2;
  __syncthreads();
  if (tid == 0)
    stats[1] = rsqrtf((wred[0] + wred[1] + wred[2] + wred[3]) * (1.0f / D) + 1e-5f);
  __syncthreads();
  float rstd = stats[1];
  for (int k = tid; k < D; k += 256)
    out[(size_t)row * D + k] = (buf[k] - mean) * rstd * g[k] + b[k];
}

// ============================ launcher ============================
extern "C" void kernel_launch(void* const* d_in, const int* in_sizes, int n_in,
                              void* d_out, int out_size, void* d_ws, size_t ws_size,
                              hipStream_t stream) {
  (void)in_sizes; (void)n_in; (void)out_size; (void)ws_size;
  const float* vf   = (const float*)d_in[0];
  const float* Wqkv = (const float*)d_in[1];
  const float* bqkv = (const float*)d_in[2];
  const float* Wo   = (const float*)d_in[3];
  const float* bo   = (const float*)d_in[4];
  const float* ln1g = (const float*)d_in[5];
  const float* ln1b = (const float*)d_in[6];
  const float* W1   = (const float*)d_in[7];
  const float* b1   = (const float*)d_in[8];
  const float* W2   = (const float*)d_in[9];
  const float* b2   = (const float*)d_in[10];
  const float* ln2g = (const float*)d_in[11];
  const float* ln2b = (const float*)d_in[12];

  float* ws = (float*)d_ws;
  float*  tok   = ws;                                // 8000*768
  float*  norms = ws + 6144000;                      // 8000
  float4* part  = (float4*)(ws + 6152000);           // up to 4000*125 float4
  int2*   pairs = (int2*)(ws + 8152000);             // up to 4000 int2
  float*  qkv   = ws + 8160000;                      // 2000*2304
  float*  attnb = ws + 12768000;                     // 2000*768
  float*  projb = ws + 8160000;                      // reuse (qkv dead)
  float*  hid   = ws + 8160000;                      // reuse 1500*3072
  float*  ffnb  = ws + 12768000;                     // reuse (attnb dead)
  float*  outp  = (float*)d_out;

  copy_f4<<<6000, 256, 0, stream>>>((const float4*)vf, (float4*)tok, 1536000);

  // ---- merge 1: 8000 -> 4000, wa=wb=0.5 ----
  norms_k<<<8000, 64, 0, stream>>>(tok, norms, 8000);
  sim_top2_v2<<<dim3(125, 63), 256, 0, stream>>>(tok, norms, 4000, 8000, 125, part);
  top2_reduce<<<(4000 + 255) / 256, 256, 0, stream>>>(part, 4000, 125, pairs);
  merge_scan5<<<12, 64, 0, stream>>>(tok, pairs, 4000, 0.5f, 0.5f);

  // ---- merge 2: 4000 -> 2000, wa=wb=0.5 ----
  norms_k<<<4000, 64, 0, stream>>>(tok, norms, 4000);
  sim_top2_v2<<<dim3(63, 32), 256, 0, stream>>>(tok, norms, 2000, 4000, 63, part);
  top2_reduce<<<(2000 + 255) / 256, 256, 0, stream>>>(part, 2000, 63, pairs);
  merge_scan5<<<12, 64, 0, stream>>>(tok, pairs, 2000, 0.5f, 0.5f);

  // ---- MHA over 2000 tokens ----
  gemm_nt_v2<<<dim3(36, 32), 256, 0, stream>>>(tok, Wqkv, bqkv, qkv, 2000, 2304, 768, 0);
  attn_k5<<<dim3(2000 / QT5, 8), 512, 0, stream>>>(qkv, attnb, 2000);
  gemm_nt_v2<<<dim3(12, 32), 256, 0, stream>>>(attnb, Wo, bo, projb, 2000, 768, 768, 0);
  res_ln<<<2000, 256, 0, stream>>>(tok, projb, ln1g, ln1b, tok, 2000);

  // ---- merge 3: 2000 -> 1500, wa=0.6, wb=0.4 ----
  norms_k<<<2000, 64, 0, stream>>>(tok, norms, 2000);
  sim_top2_v2<<<dim3(32, 8), 256, 0, stream>>>(tok, norms, 500, 2000, 32, part);
  top2_reduce<<<(500 + 255) / 256, 256, 0, stream>>>(part, 500, 32, pairs);
  merge_scan5<<<12, 64, 0, stream>>>(tok, pairs, 500, 0.6f, 0.4f);

  // ---- FFN + final LN -> d_out ----
  gemm_nt_v2<<<dim3(48, 24), 256, 0, stream>>>(tok, W1, b1, hid, 1500, 3072, 768, 1);
  gemm_nt_v2<<<dim3(12, 24), 256, 0, stream>>>(hid, W2, b2, ffnb, 1500, 768, 3072, 0);
  res_ln<<<1500, 256, 0, stream>>>(tok, ffnb, ln2g, ln2b, outp, 1500);
}